// Round 12
// baseline (431.736 us; speedup 1.0000x reference)
//
#include <hip/hip_runtime.h>
#include <hip/hip_fp16.h>
#include <cfloat>
#include <cstdint>
#include <cstddef>

#define N_NODES 100000
#define N_EDGES 1600000
#define G_GRAPHS 64
#define BKT_SHIFT 9
#define BKT_NODES (1 << BKT_SHIFT)                              // 512
#define NBKT ((N_NODES + BKT_NODES - 1) >> BKT_SHIFT)           // 196
#define CSR_CAP (N_EDGES + 3 * N_NODES + 64)                    // padded CSR

// ---------------------------------------------------------------------------
// Dual GEMM, single-pass: O0 = act(A)@W0 (fp16 if HALF0), O1 = act(A)@W1.
// ---------------------------------------------------------------------------
template <int K, int J, bool FUSE, bool HALF0>
__launch_bounds__(256) __global__
void gemm_dual(const float* __restrict__ A, const float* __restrict__ W0,
               const float* __restrict__ W1, const float* __restrict__ bias,
               void* __restrict__ O0v, float* __restrict__ O1, int n) {
  constexpr int BK = 64;
  constexpr int CPT = J / 32;
  __shared__ __align__(16) float As[32][BK];
  __shared__ __align__(16) float W0t[J][BK + 4];
  __shared__ __align__(16) float W1t[J][BK + 4];
  const int tid = threadIdx.x;
  const int n0 = blockIdx.x * 32;
  const int tr = tid >> 5;
  const int tc = tid & 31;

  float acc[4][CPT][2];
#pragma unroll
  for (int i = 0; i < 4; ++i)
#pragma unroll
    for (int j = 0; j < CPT; ++j) {
      acc[i][j][0] = 0.f;
      acc[i][j][1] = 0.f;
    }

  for (int kc = 0; kc < K; kc += BK) {
    for (int i = tid; i < 32 * BK / 4; i += 256) {
      const int node = i / (BK / 4);
      const int kg = i % (BK / 4);
      float4 v = make_float4(0.f, 0.f, 0.f, 0.f);
      if (n0 + node < n) {
        v = reinterpret_cast<const float4*>(
            A)[(size_t)(n0 + node) * (K / 4) + kc / 4 + kg];
        if constexpr (FUSE) {
          const float4 b =
              reinterpret_cast<const float4*>(bias)[kc / 4 + kg];
          v.x = fmaxf(v.x + b.x, 0.f);
          v.y = fmaxf(v.y + b.y, 0.f);
          v.z = fmaxf(v.z + b.z, 0.f);
          v.w = fmaxf(v.w + b.w, 0.f);
        }
      }
      reinterpret_cast<float4*>(&As[node][0])[kg] = v;
    }
    for (int i = tid; i < BK * J; i += 256) {
      const int k = i / J;
      const int j = i % J;
      W0t[j][k] = W0[(size_t)(kc + k) * J + j];
      W1t[j][k] = W1[(size_t)(kc + k) * J + j];
    }
    __syncthreads();

#pragma unroll 2
    for (int k4 = 0; k4 < BK / 4; ++k4) {
      float4 a[4];
#pragma unroll
      for (int i = 0; i < 4; ++i)
        a[i] = reinterpret_cast<const float4*>(&As[tr * 4 + i][0])[k4];
      float4 w0[CPT], w1[CPT];
#pragma unroll
      for (int j = 0; j < CPT; ++j) {
        w0[j] = *reinterpret_cast<const float4*>(&W0t[tc + 32 * j][k4 * 4]);
        w1[j] = *reinterpret_cast<const float4*>(&W1t[tc + 32 * j][k4 * 4]);
      }
#pragma unroll
      for (int i = 0; i < 4; ++i)
#pragma unroll
        for (int j = 0; j < CPT; ++j) {
          acc[i][j][0] = fmaf(a[i].x, w0[j].x, acc[i][j][0]);
          acc[i][j][0] = fmaf(a[i].y, w0[j].y, acc[i][j][0]);
          acc[i][j][0] = fmaf(a[i].z, w0[j].z, acc[i][j][0]);
          acc[i][j][0] = fmaf(a[i].w, w0[j].w, acc[i][j][0]);
          acc[i][j][1] = fmaf(a[i].x, w1[j].x, acc[i][j][1]);
          acc[i][j][1] = fmaf(a[i].y, w1[j].y, acc[i][j][1]);
          acc[i][j][1] = fmaf(a[i].z, w1[j].z, acc[i][j][1]);
          acc[i][j][1] = fmaf(a[i].w, w1[j].w, acc[i][j][1]);
        }
    }
    __syncthreads();
  }

#pragma unroll
  for (int i = 0; i < 4; ++i) {
    const int node = n0 + tr * 4 + i;
    if (node < n) {
      if constexpr (HALF0) {
        __half* O0 = (__half*)O0v;
#pragma unroll
        for (int j = 0; j < CPT; ++j)
          O0[(size_t)node * J + tc + 32 * j] = __float2half(acc[i][j][0]);
      } else {
        float* O0 = (float*)O0v;
#pragma unroll
        for (int j = 0; j < CPT; ++j)
          O0[(size_t)node * J + tc + 32 * j] = acc[i][j][0];
      }
#pragma unroll
      for (int j = 0; j < CPT; ++j)
        O1[(size_t)node * J + tc + 32 * j] = acc[i][j][1];
    }
  }
}

// ---------------------------------------------------------------------------
// CSR build (padded to 4-edge multiples per node):
// bucket hist -> bucket scan -> partition -> partB1 (deg + padded local
// offsets + bucket padded totals) -> pbscan -> partB2 (scatter + pad fill).
// ---------------------------------------------------------------------------
__launch_bounds__(256) __global__
void histB_kernel(const int* __restrict__ ei, int* __restrict__ bhist) {
  __shared__ int lb[NBKT];
  for (int i = threadIdx.x; i < NBKT; i += 256) lb[i] = 0;
  __syncthreads();
  const int e0 = blockIdx.x * 1024 + threadIdx.x;
#pragma unroll
  for (int k = 0; k < 4; ++k) {
    const int e = e0 + k * 256;
    if (e < N_EDGES) atomicAdd(&lb[ei[N_EDGES + e] >> BKT_SHIFT], 1);
  }
  __syncthreads();
  for (int i = threadIdx.x; i < NBKT; i += 256)
    if (lb[i]) atomicAdd(&bhist[i], lb[i]);
}

__launch_bounds__(256) __global__
void bscan_kernel(const int* __restrict__ bhist, int* __restrict__ bbase,
                  int* __restrict__ bcursor) {
  __shared__ int ls[256];
  const int tid = threadIdx.x;
  const int v = (tid < NBKT) ? bhist[tid] : 0;
  ls[tid] = v;
  __syncthreads();
  for (int d = 1; d < 256; d <<= 1) {
    const int t = (tid >= d) ? ls[tid - d] : 0;
    __syncthreads();
    ls[tid] += t;
    __syncthreads();
  }
  if (tid < NBKT) {
    const int ex = ls[tid] - v;
    bbase[tid] = ex;
    bcursor[tid] = ex;
  }
}

__launch_bounds__(256) __global__
void pbscan_kernel(const int* __restrict__ pbsum, int* __restrict__ pboff) {
  __shared__ int ls[256];
  const int tid = threadIdx.x;
  const int v = (tid < NBKT) ? pbsum[tid] : 0;
  ls[tid] = v;
  __syncthreads();
  for (int d = 1; d < 256; d <<= 1) {
    const int t = (tid >= d) ? ls[tid - d] : 0;
    __syncthreads();
    ls[tid] += t;
    __syncthreads();
  }
  if (tid < NBKT) pboff[tid] = ls[tid] - v;
}

__launch_bounds__(1024) __global__
void partA_kernel(const int* __restrict__ ei, int* __restrict__ bcursor,
                  int2* __restrict__ staging) {
  __shared__ int lh[NBKT];
  __shared__ int lbase[NBKT];
  const int tid = threadIdx.x;
  for (int i = tid; i < NBKT; i += 1024) lh[i] = 0;
  __syncthreads();
  const int e0 = blockIdx.x * 4096 + tid;
  int s[4], d[4];
#pragma unroll
  for (int k = 0; k < 4; ++k) {
    const int e = e0 + k * 1024;
    const bool ok = e < N_EDGES;
    s[k] = ok ? ei[e] : 0;
    d[k] = ok ? ei[N_EDGES + e] : -1;
    if (ok) atomicAdd(&lh[d[k] >> BKT_SHIFT], 1);
  }
  __syncthreads();
  for (int i = tid; i < NBKT; i += 1024) {
    const int c = lh[i];
    lbase[i] = c ? atomicAdd(&bcursor[i], c) : 0;
    lh[i] = 0;
  }
  __syncthreads();
#pragma unroll
  for (int k = 0; k < 4; ++k) {
    if (d[k] >= 0) {
      const int b = d[k] >> BKT_SHIFT;
      const int p = lbase[b] + atomicAdd(&lh[b], 1);
      staging[p] = make_int2(s[k], d[k]);
    }
  }
}

// partB1: per-bucket deg count (LDS) + padded 512-scan -> deg, local row,
// per-bucket padded total.
__launch_bounds__(256) __global__
void partB1_kernel(const int2* __restrict__ staging,
                   const int* __restrict__ bbase, const int* __restrict__ bhist,
                   int* __restrict__ deg, int* __restrict__ row,
                   int* __restrict__ pbsum) {
  __shared__ int ldeg[BKT_NODES];
  __shared__ int lsc[256];
  const int b = blockIdx.x;
  const int tid = threadIdx.x;
  const int node0 = b << BKT_SHIFT;
  ldeg[2 * tid] = 0;
  ldeg[2 * tid + 1] = 0;
  __syncthreads();
  const int start = bbase[b];
  const int cnt = bhist[b];
  for (int i = tid; i < cnt; i += 256)
    atomicAdd(&ldeg[staging[start + i].y - node0], 1);
  __syncthreads();
  const int d0 = ldeg[2 * tid];
  const int d1 = ldeg[2 * tid + 1];
  const int p0 = (d0 + 3) & ~3;
  const int p1 = (d1 + 3) & ~3;
  const int psum = p0 + p1;
  lsc[tid] = psum;
  __syncthreads();
  for (int d = 1; d < 256; d <<= 1) {
    const int t = (tid >= d) ? lsc[tid - d] : 0;
    __syncthreads();
    lsc[tid] += t;
    __syncthreads();
  }
  const int ex = lsc[tid] - psum;  // local padded offset
  const int n0 = node0 + 2 * tid;
  if (n0 < N_NODES) {
    deg[n0] = d0;
    row[n0] = ex;
  }
  if (n0 + 1 < N_NODES) {
    deg[n0 + 1] = d1;
    row[n0 + 1] = ex + p0;
  }
  if (tid == 255) pbsum[b] = lsc[255];
}

// partB2: finalize row (+bucket offset), pad-fill, local scatter.
__launch_bounds__(256) __global__
void partB2_kernel(const int2* __restrict__ staging,
                   const int* __restrict__ bbase, const int* __restrict__ bhist,
                   const int* __restrict__ pboff, const int* __restrict__ pbsum,
                   const int* __restrict__ deg, int* __restrict__ row,
                   int* __restrict__ csr_src) {
  __shared__ int lcur[BKT_NODES];
  const int b = blockIdx.x;
  const int tid = threadIdx.x;
  const int node0 = b << BKT_SHIFT;
  const int off = pboff[b];
  const int n0 = node0 + 2 * tid;
  int r0a = 0, r1a = 0, d0 = 0, d1 = 0;
  if (n0 < N_NODES) {
    r0a = row[n0] + off;
    d0 = deg[n0];
    row[n0] = r0a;
  }
  if (n0 + 1 < N_NODES) {
    r1a = row[n0 + 1] + off;
    d1 = deg[n0 + 1];
    row[n0 + 1] = r1a;
  }
  lcur[2 * tid] = r0a;
  lcur[2 * tid + 1] = r1a;
  // pad fill (independent of scatter)
  const int p0e = (d0 + 3) & ~3;
  const int p1e = (d1 + 3) & ~3;
  if (n0 < N_NODES)
    for (int p = d0; p < p0e; ++p) csr_src[r0a + p] = 0;
  if (n0 + 1 < N_NODES)
    for (int p = d1; p < p1e; ++p) csr_src[r1a + p] = 0;
  if (b == NBKT - 1) {  // zero the prefetch tail beyond the padded CSR
    const int end = off + pbsum[b];
    for (int i = tid; i < 64; i += 256) csr_src[end + i] = 0;
  }
  __syncthreads();
  const int start = bbase[b];
  const int cnt = bhist[b];
  for (int i = tid; i < cnt; i += 256) {
    const int2 e = staging[start + i];
    const int p = atomicAdd(&lcur[e.y - node0], 1);
    csr_src[p] = e.x;
  }
}

// ---------------------------------------------------------------------------
// Layer 1 fused softmax-aggregate. H=2, C=32. One wave per node; four
// 16-lane groups process 4 edges at once, each lane holds a channel QUAD
// (fp16x4 = 8 B gather). 8-lane subgroups align with the 2 heads.
// ---------------------------------------------------------------------------
__launch_bounds__(256) __global__
void gat1_kernel(const __half* __restrict__ xlh, const float* __restrict__ xr,
                 const float* __restrict__ att, const int* __restrict__ row,
                 const int* __restrict__ deg, const int* __restrict__ csr_src,
                 float* __restrict__ agg) {
  const int n =
      __builtin_amdgcn_readfirstlane(blockIdx.x * 4 + (threadIdx.x >> 6));
  if (n >= N_NODES) return;
  const int lane = threadIdx.x & 63;
  const int g = (lane >> 4) & 3;  // edge group 0..3
  const int m = lane & 15;        // channel quad: channels 4m..4m+3
  const int r0 = __builtin_amdgcn_readfirstlane(row[n]);  // 4-aligned
  const int dg = __builtin_amdgcn_readfirstlane(deg[n]);

  const float4 xrv =
      *reinterpret_cast<const float4*>(xr + ((size_t)n << 6) + 4 * m);
  const float4 attv = *reinterpret_cast<const float4*>(att + 4 * m);
  const int4* __restrict__ idxp =
      reinterpret_cast<const int4*>(csr_src + r0);

  float s = 0.f;
  float4 acc = make_float4(0.f, 0.f, 0.f, 0.f);
  const int T = (dg + 3) >> 2;  // rounds of 4 edges

  uint2 xb0, xb1;
  {
    const int4 q0 = idxp[0];
    const int4 q1 = idxp[1];
    int lo = (g & 1) ? q0.y : q0.x, hi = (g & 1) ? q0.w : q0.z;
    const int s0 = __builtin_amdgcn_readfirstlane(0) | ((g & 2) ? hi : lo);
    lo = (g & 1) ? q1.y : q1.x;
    hi = (g & 1) ? q1.w : q1.z;
    const int s1 = (g & 2) ? hi : lo;
    xb0 = *reinterpret_cast<const uint2*>(
        (const char*)xlh + (((size_t)(unsigned)s0) << 7) + 8 * m);
    xb1 = *reinterpret_cast<const uint2*>(
        (const char*)xlh + (((size_t)(unsigned)s1) << 7) + 8 * m);
  }
  for (int t = 0; t < T; ++t) {
    const int4 qn = idxp[t + 2];
    const int lo = (g & 1) ? qn.y : qn.x, hi = (g & 1) ? qn.w : qn.z;
    const int sn = (g & 2) ? hi : lo;
    const uint2 xn = *reinterpret_cast<const uint2*>(
        (const char*)xlh + (((size_t)(unsigned)sn) << 7) + 8 * m);

    const float2 a01 = __half22float2(((const __half2*)&xb0)[0]);
    const float2 a23 = __half22float2(((const __half2*)&xb0)[1]);
    float v0 = a01.x + xrv.x, v1 = a01.y + xrv.y;
    float v2 = a23.x + xrv.z, v3 = a23.y + xrv.w;
    v0 = fmaxf(v0, 0.2f * v0);
    v1 = fmaxf(v1, 0.2f * v1);
    v2 = fmaxf(v2, 0.2f * v2);
    v3 = fmaxf(v3, 0.2f * v3);
    float p = v0 * attv.x;
    p = fmaf(v1, attv.y, p);
    p = fmaf(v2, attv.z, p);
    p = fmaf(v3, attv.w, p);
    p += __shfl_xor(p, 1);
    p += __shfl_xor(p, 2);
    p += __shfl_xor(p, 4);  // per-head (8-lane) sum
    float e = __expf(p);
    e = (4 * t + g < dg) ? e : 0.f;
    s += e;
    acc.x = fmaf(e, a01.x, acc.x);
    acc.y = fmaf(e, a01.y, acc.y);
    acc.z = fmaf(e, a23.x, acc.z);
    acc.w = fmaf(e, a23.y, acc.w);
    xb0 = xb1;
    xb1 = xn;
  }
  // merge the 4 edge groups
  s += __shfl_xor(s, 16);
  s += __shfl_xor(s, 32);
  acc.x += __shfl_xor(acc.x, 16);
  acc.x += __shfl_xor(acc.x, 32);
  acc.y += __shfl_xor(acc.y, 16);
  acc.y += __shfl_xor(acc.y, 32);
  acc.z += __shfl_xor(acc.z, 16);
  acc.z += __shfl_xor(acc.z, 32);
  acc.w += __shfl_xor(acc.w, 16);
  acc.w += __shfl_xor(acc.w, 32);
  const float inv = s > 0.f ? 1.f / s : 0.f;
  if (g == 0)
    *reinterpret_cast<float4*>(agg + ((size_t)n << 6) + 4 * m) =
        make_float4(acc.x * inv, acc.y * inv, acc.z * inv, acc.w * inv);
}

// ---------------------------------------------------------------------------
// Layer 2 fused: H=1, C=32. Eight 8-lane groups process 8 edges at once,
// each lane holds a channel quad (8 B gather = row is 64 B). Butterfly
// merges leave all lanes with the full result. Epilogue: bias+relu -> h2,
// gate scalar inline.
// ---------------------------------------------------------------------------
__launch_bounds__(256) __global__
void gat2_kernel(const __half* __restrict__ xlh, const float* __restrict__ xr,
                 const float* __restrict__ att, const int* __restrict__ row,
                 const int* __restrict__ deg, const int* __restrict__ csr_src,
                 const float* __restrict__ b2, const float* __restrict__ g1w,
                 const float* __restrict__ g1b, const float* __restrict__ g2w,
                 const float* __restrict__ g2b, float* __restrict__ h2,
                 float* __restrict__ gate) {
  const int n =
      __builtin_amdgcn_readfirstlane(blockIdx.x * 4 + (threadIdx.x >> 6));
  if (n >= N_NODES) return;
  const int lane = threadIdx.x & 63;
  const int g = lane >> 3;  // edge group 0..7
  const int m = lane & 7;   // channel quad: channels 4m..4m+3

  const int r0 = __builtin_amdgcn_readfirstlane(row[n]);
  const int dg = __builtin_amdgcn_readfirstlane(deg[n]);

  const float4 xrv =
      *reinterpret_cast<const float4*>(xr + (size_t)n * 32 + 4 * m);
  const float4 attv = *reinterpret_cast<const float4*>(att + 4 * m);
  const int4* __restrict__ idxp =
      reinterpret_cast<const int4*>(csr_src + r0);

  float s = 0.f;
  float4 acc = make_float4(0.f, 0.f, 0.f, 0.f);
  const int T = (dg + 7) >> 3;  // rounds of 8 edges

  auto pick8 = [&](int4 qa, int4 qb) -> int {
    const int a0 = (g & 1) ? qa.y : qa.x;
    const int a1 = (g & 1) ? qa.w : qa.z;
    const int a2 = (g & 1) ? qb.y : qb.x;
    const int a3 = (g & 1) ? qb.w : qb.z;
    const int b0 = (g & 2) ? a1 : a0;
    const int b1 = (g & 2) ? a3 : a2;
    return (g & 4) ? b1 : b0;
  };

  uint2 xb0, xb1;
  {
    const int s0 = pick8(idxp[0], idxp[1]);
    const int s1 = pick8(idxp[2], idxp[3]);
    xb0 = *reinterpret_cast<const uint2*>(
        (const char*)xlh + (((size_t)(unsigned)s0) << 6) + 8 * m);
    xb1 = *reinterpret_cast<const uint2*>(
        (const char*)xlh + (((size_t)(unsigned)s1) << 6) + 8 * m);
  }
  for (int t = 0; t < T; ++t) {
    const int sn = pick8(idxp[2 * t + 4], idxp[2 * t + 5]);
    const uint2 xn = *reinterpret_cast<const uint2*>(
        (const char*)xlh + (((size_t)(unsigned)sn) << 6) + 8 * m);

    const float2 a01 = __half22float2(((const __half2*)&xb0)[0]);
    const float2 a23 = __half22float2(((const __half2*)&xb0)[1]);
    float v0 = a01.x + xrv.x, v1 = a01.y + xrv.y;
    float v2 = a23.x + xrv.z, v3 = a23.y + xrv.w;
    v0 = fmaxf(v0, 0.2f * v0);
    v1 = fmaxf(v1, 0.2f * v1);
    v2 = fmaxf(v2, 0.2f * v2);
    v3 = fmaxf(v3, 0.2f * v3);
    float p = v0 * attv.x;
    p = fmaf(v1, attv.y, p);
    p = fmaf(v2, attv.z, p);
    p = fmaf(v3, attv.w, p);
    p += __shfl_xor(p, 1);
    p += __shfl_xor(p, 2);
    p += __shfl_xor(p, 4);  // per-edge (8-lane) sum
    float e = __expf(p);
    e = (8 * t + g < dg) ? e : 0.f;
    s += e;
    acc.x = fmaf(e, a01.x, acc.x);
    acc.y = fmaf(e, a01.y, acc.y);
    acc.z = fmaf(e, a23.x, acc.z);
    acc.w = fmaf(e, a23.y, acc.w);
    xb0 = xb1;
    xb1 = xn;
  }
  // merge the 8 edge groups (all lanes get totals)
  s += __shfl_xor(s, 8);
  s += __shfl_xor(s, 16);
  s += __shfl_xor(s, 32);
  acc.x += __shfl_xor(acc.x, 8);
  acc.x += __shfl_xor(acc.x, 16);
  acc.x += __shfl_xor(acc.x, 32);
  acc.y += __shfl_xor(acc.y, 8);
  acc.y += __shfl_xor(acc.y, 16);
  acc.y += __shfl_xor(acc.y, 32);
  acc.z += __shfl_xor(acc.z, 8);
  acc.z += __shfl_xor(acc.z, 16);
  acc.z += __shfl_xor(acc.z, 32);
  acc.w += __shfl_xor(acc.w, 8);
  acc.w += __shfl_xor(acc.w, 16);
  acc.w += __shfl_xor(acc.w, 32);
  const float inv = s > 0.f ? 1.f / s : 0.f;
  const float4 b2v = *reinterpret_cast<const float4*>(b2 + 4 * m);
  const float4 hv4 = make_float4(fmaxf(acc.x * inv + b2v.x, 0.f),
                                 fmaxf(acc.y * inv + b2v.y, 0.f),
                                 fmaxf(acc.z * inv + b2v.z, 0.f),
                                 fmaxf(acc.w * inv + b2v.w, 0.f));
  if (g == 0)
    *reinterpret_cast<float4*>(h2 + (size_t)n * 32 + 4 * m) = hv4;

  // redistribute to 1-channel-per-lane for the gate matvec
  const int c = lane & 31;
  const float h0 = __shfl(hv4.x, c >> 2, 32);
  const float h1 = __shfl(hv4.y, c >> 2, 32);
  const float h2c = __shfl(hv4.z, c >> 2, 32);
  const float h3 = __shfl(hv4.w, c >> 2, 32);
  const float lo = (c & 1) ? h1 : h0;
  const float hi = (c & 1) ? h3 : h2c;
  const float hv = (c & 2) ? hi : lo;
  float sg = g1b[c];
#pragma unroll
  for (int k = 0; k < 32; ++k)
    sg = fmaf(__shfl(hv, k, 32), g1w[k * 32 + c], sg);
  sg = fmaxf(sg, 0.f);
  float pg = sg * g2w[c];
  pg += __shfl_xor(pg, 1);
  pg += __shfl_xor(pg, 2);
  pg += __shfl_xor(pg, 4);
  pg += __shfl_xor(pg, 8);
  pg += __shfl_xor(pg, 16);
  if (lane == 0) gate[n] = pg + g2b[0];
}

// ---------------------------------------------------------------------------
__launch_bounds__(256) __global__
void gepool_kernel(const float* __restrict__ h2, const int* __restrict__ batch,
                   const float* __restrict__ gate, float* __restrict__ gd,
                   float* __restrict__ pooled) {
  __shared__ float pool[G_GRAPHS * 32];
  __shared__ float gdb[G_GRAPHS];
  const int tid = threadIdx.x;
  for (int i = tid; i < G_GRAPHS * 32; i += 256) pool[i] = 0.f;
  if (tid < G_GRAPHS) gdb[tid] = 0.f;
  __syncthreads();
  const int c = tid & 31;
  const int hw = tid >> 5;
  const int start = blockIdx.x * 256;
  const int end = min(N_NODES, start + 256);
  for (int n = start + hw; n < end; n += 8) {
    const int b = batch[n];
    const float ge = __expf(gate[n]);
    atomicAdd(&pool[b * 32 + c], ge * h2[(size_t)n * 32 + c]);
    if (c == 0) atomicAdd(&gdb[b], ge);
  }
  __syncthreads();
  for (int i = tid; i < G_GRAPHS * 32; i += 256)
    if (pool[i] != 0.f) unsafeAtomicAdd(&pooled[i], pool[i]);
  if (tid < G_GRAPHS && gdb[tid] != 0.f) unsafeAtomicAdd(&gd[tid], gdb[tid]);
}

__launch_bounds__(64) __global__
void final_kernel(const float* __restrict__ pooled, const float* __restrict__ gd,
                  const float* __restrict__ l1w, const float* __restrict__ l1b,
                  const float* __restrict__ l2w, const float* __restrict__ l2b,
                  float* __restrict__ out) {
  const int g = blockIdx.x;
  const int lane = threadIdx.x;
  if (lane >= 32) return;
  const float invgd = 1.f / gd[g];
  float s = l1b[lane];
#pragma unroll
  for (int k = 0; k < 32; ++k)
    s = fmaf(pooled[g * 32 + k] * invgd, l1w[k * 32 + lane], s);
  s = fmaxf(s, 0.f);
  float p = s * l2w[lane];
  p += __shfl_xor(p, 1);
  p += __shfl_xor(p, 2);
  p += __shfl_xor(p, 4);
  p += __shfl_xor(p, 8);
  p += __shfl_xor(p, 16);
  if (lane == 0) out[g] = p + l2b[0];
}

// ---------------------------------------------------------------------------
extern "C" void kernel_launch(void* const* d_in, const int* in_sizes, int n_in,
                              void* d_out, int out_size, void* d_ws,
                              size_t ws_size, hipStream_t stream) {
  const float* x    = (const float*)d_in[0];
  const int*   ei   = (const int*)d_in[1];
  const int*   batch= (const int*)d_in[2];
  const float* Wl1  = (const float*)d_in[3];
  const float* Wr1  = (const float*)d_in[4];
  const float* att1 = (const float*)d_in[5];
  const float* b1   = (const float*)d_in[6];
  const float* Wl2  = (const float*)d_in[7];
  const float* Wr2  = (const float*)d_in[8];
  const float* att2 = (const float*)d_in[9];
  const float* b2   = (const float*)d_in[10];
  const float* g1w  = (const float*)d_in[11];
  const float* g1b  = (const float*)d_in[12];
  const float* g2w  = (const float*)d_in[13];
  const float* g2b  = (const float*)d_in[14];
  const float* l1w  = (const float*)d_in[15];
  const float* l1b  = (const float*)d_in[16];
  const float* l2w  = (const float*)d_in[17];
  const float* l2b  = (const float*)d_in[18];
  float* out = (float*)d_out;

  // ---- workspace layout (csr_src 16B-aligned; staging 8B-aligned) ----
  int* bhist   = (int*)d_ws;            // NBKT (zeroed)
  int* bbase   = bhist + NBKT;          // NBKT
  int* bcursor = bbase + NBKT;          // NBKT
  int* pbsum   = bcursor + NBKT;        // NBKT
  int* pboff   = pbsum + NBKT;          // NBKT  (5*196 = 980 ints)
  int* deg     = pboff + NBKT;          // N
  int* row     = deg + N_NODES;         // N    (980+200000 ≡ 0 mod 4)
  int* csr_src = row + N_NODES;         // CSR_CAP (16B-aligned)
  int2* staging = (int2*)(csr_src + CSR_CAP);       // E int2
  float* fbase = (float*)(staging + N_EDGES);
  float* xr1  = fbase;                         // N*64
  float* agg1 = xr1 + (size_t)N_NODES * 64;    // N*64
  float* gate = agg1 + (size_t)N_NODES * 64;   // N
  float* gd   = gate + N_NODES;                // 64
  float* pooled = gd + G_GRAPHS;               // 64*32
  __half* xl1h = (__half*)(pooled + G_GRAPHS * 32);  // N*64 half
  // layer-2 aliases (stream-ordered producers/consumers)
  __half* xl2h = xl1h;                         // N*32 half
  float* xr2 = xr1;                            // N*32 (first half of xr1)
  float* h2  = xr1 + (size_t)N_NODES * 32;     // N*32 (second half of xr1)

  hipMemsetAsync(bhist, 0, (size_t)NBKT * sizeof(int), stream);
  hipMemsetAsync(gd, 0, (size_t)(G_GRAPHS + G_GRAPHS * 32) * sizeof(float), stream);

  // CSR build (padded): hist -> scan -> partition -> B1 -> pbscan -> B2
  histB_kernel<<<(N_EDGES + 1023) / 1024, 256, 0, stream>>>(ei, bhist);
  bscan_kernel<<<1, 256, 0, stream>>>(bhist, bbase, bcursor);
  partA_kernel<<<(N_EDGES + 4095) / 4096, 1024, 0, stream>>>(ei, bcursor,
                                                             staging);
  partB1_kernel<<<NBKT, 256, 0, stream>>>(staging, bbase, bhist, deg, row,
                                          pbsum);
  pbscan_kernel<<<1, 256, 0, stream>>>(pbsum, pboff);
  partB2_kernel<<<NBKT, 256, 0, stream>>>(staging, bbase, bhist, pboff, pbsum,
                                          deg, row, csr_src);

  // Layer 1 (xl staged fp16)
  gemm_dual<128, 64, false, true><<<(N_NODES + 31) / 32, 256, 0, stream>>>(
      x, Wl1, Wr1, nullptr, (void*)xl1h, xr1, N_NODES);
  gat1_kernel<<<(N_NODES + 3) / 4, 256, 0, stream>>>(xl1h, xr1, att1, row, deg,
                                                     csr_src, agg1);

  // Layer 2 (bias1+relu fused into A-load; gate fused into epilogue)
  gemm_dual<64, 32, true, true><<<(N_NODES + 31) / 32, 256, 0, stream>>>(
      agg1, Wl2, Wr2, b1, (void*)xl2h, xr2, N_NODES);
  gat2_kernel<<<(N_NODES + 3) / 4, 256, 0, stream>>>(
      xl2h, xr2, att2, row, deg, csr_src, b2, g1w, g1b, g2w, g2b, h2, gate);

  // Pooling + head (no-max graph softmax)
  gepool_kernel<<<(N_NODES + 255) / 256, 256, 0, stream>>>(h2, batch, gate, gd,
                                                           pooled);
  final_kernel<<<64, 64, 0, stream>>>(pooled, gd, l1w, l1b, l2w, l2b, out);
}